// Round 1
// baseline (673.964 us; speedup 1.0000x reference)
//
#include <hip/hip_runtime.h>
#include <math.h>

// ---------------------------------------------------------------------------
// CellTypeGNN: 2x [SAGE(mean) -> LN -> GELU -> +res] -> SAGE -> GELU -> LN -> Linear
// N=50000, E=800000, D=128, DOUT(conv3)=64, classes=40. fp32 throughout.
// ---------------------------------------------------------------------------

#define WAVE 64

__device__ inline float gelu_f(float x) {
    return 0.5f * x * (1.0f + erff(x * 0.70710678118654752440f));
}

__device__ inline float wave_sum(float v) {
#pragma unroll
    for (int d = 32; d > 0; d >>= 1) v += __shfl_xor(v, d);
    return v;
}

// ---------------- CSR build ----------------

__global__ void k_count(const int* __restrict__ dst, int* __restrict__ cnt, int e) {
    int t = blockIdx.x * blockDim.x + threadIdx.x;
    int stride = gridDim.x * blockDim.x;
    for (int i = t; i < e; i += stride) {
        atomicAdd(&cnt[dst[i]], 1);
    }
}

// exclusive scan of cnt[n] -> off[0..n]; also resets cnt to the exclusive
// prefix so it can serve as the fill cursor. Single block of 1024 threads.
__global__ void k_scan(int* __restrict__ cnt_cur, int* __restrict__ off, int n) {
    __shared__ int part[1024];
    const int tid = threadIdx.x;
    const int C = (n + 1023) >> 10;
    const int base = tid * C;
    int s = 0;
    for (int j = 0; j < C; ++j) {
        int ix = base + j;
        if (ix < n) s += cnt_cur[ix];
    }
    part[tid] = s;
    __syncthreads();
    for (int d = 1; d < 1024; d <<= 1) {
        int add = (tid >= d) ? part[tid - d] : 0;
        __syncthreads();
        part[tid] += add;
        __syncthreads();
    }
    int run = (tid == 0) ? 0 : part[tid - 1];
    for (int j = 0; j < C; ++j) {
        int ix = base + j;
        if (ix < n) {
            int c = cnt_cur[ix];
            off[ix] = run;
            cnt_cur[ix] = run;
            run += c;
        }
    }
    if (tid == 1023) off[n] = part[1023];
}

__global__ void k_fill(const int* __restrict__ src, const int* __restrict__ dst,
                       int* __restrict__ cur, int* __restrict__ csr, int e) {
    int t = blockIdx.x * blockDim.x + threadIdx.x;
    int stride = gridDim.x * blockDim.x;
    for (int i = t; i < e; i += stride) {
        int d = dst[i];
        int pos = atomicAdd(&cur[d], 1);
        csr[pos] = src[i];
    }
}

// ---------------- mean aggregation (wave per node) ----------------

__global__ void k_agg(const float* __restrict__ X, const int* __restrict__ off,
                      const int* __restrict__ csr, float* __restrict__ agg, int n) {
    const int wid = (blockIdx.x * blockDim.x + threadIdx.x) >> 6;
    const int lane = threadIdx.x & 63;
    const int nw = (gridDim.x * blockDim.x) >> 6;
    for (int i = wid; i < n; i += nw) {
        int s0 = off[i], s1 = off[i + 1];
        float a0 = 0.f, a1 = 0.f;
        for (int t = s0; t < s1; ++t) {
            int sidx = csr[t];
            const float* p = X + (size_t)sidx * 128;
            a0 += p[lane];
            a1 += p[64 + lane];
        }
        int deg = s1 - s0;
        float inv = 1.0f / (float)(deg > 1 ? deg : 1);
        agg[(size_t)i * 128 + lane] = a0 * inv;
        agg[(size_t)i * 128 + 64 + lane] = a1 * inv;
    }
}

// ---------------- fused SAGE GEMM: H = [Agg|Xin] @ [Wl;Wr] + bias ----------------
// BM=128 rows, BN=DOUT cols, BK=32. 256 threads, 8 rows x (DOUT/16) cols each.
// NOTE: H may alias Agg (row ownership of A-tile == row ownership of C-tile,
// and all global A reads complete before the final __syncthreads preceding the
// stores), so Agg/H are deliberately NOT __restrict__.

template <int DOUT, bool GELU_EPI>
__global__ __launch_bounds__(256) void k_gemm(const float* Agg, const float* __restrict__ Xin,
                                              const float* __restrict__ Wl,
                                              const float* __restrict__ Wr,
                                              const float* __restrict__ bias, float* H, int n) {
    __shared__ float As[128][33];
    __shared__ float Ws[32][DOUT];
    const int tid = threadIdx.x;
    const int tx = tid & 15;
    const int ty = tid >> 4;
    constexpr int CPT = DOUT / 16;  // 8 or 4
    const int row0 = blockIdx.x * 128;

    float acc[8][CPT];
#pragma unroll
    for (int i = 0; i < 8; ++i)
#pragma unroll
        for (int u = 0; u < CPT; ++u) acc[i][u] = 0.f;

    for (int k0 = 0; k0 < 256; k0 += 32) {
        const float* Asrc = (k0 < 128) ? Agg : Xin;
        const int kk = k0 & 127;
        // A tile: rows row0..row0+127, cols kk..kk+31 (row-major in LDS, +1 pad)
        {
            const int m = tid >> 1;
            const int cb = (tid & 1) * 16;
            int gr = row0 + m;
            if (gr > n - 1) gr = n - 1;
            const float* p = Asrc + (size_t)gr * 128 + kk + cb;
#pragma unroll
            for (int j = 0; j < 4; ++j) {
                float4 v = *(const float4*)(p + j * 4);
                As[m][cb + j * 4 + 0] = v.x;
                As[m][cb + j * 4 + 1] = v.y;
                As[m][cb + j * 4 + 2] = v.z;
                As[m][cb + j * 4 + 3] = v.w;
            }
        }
        // W tile: 32 rows x DOUT cols of Wl (k<128) or Wr
        {
            const float* Wsrc = ((k0 < 128) ? Wl : Wr) + (size_t)kk * DOUT;
            constexpr int FPT = (32 * DOUT) / 256;  // 16 or 8 floats per thread
#pragma unroll
            for (int j = 0; j < FPT / 4; ++j) {
                int flat = tid * FPT + j * 4;
                int r = flat / DOUT, c = flat % DOUT;
                float4 v = *(const float4*)(Wsrc + (size_t)r * DOUT + c);
                *(float4*)&Ws[r][c] = v;
            }
        }
        __syncthreads();
#pragma unroll
        for (int k = 0; k < 32; ++k) {
            float a[8], wv[CPT];
#pragma unroll
            for (int i = 0; i < 8; ++i) a[i] = As[ty * 8 + i][k];
#pragma unroll
            for (int u = 0; u < CPT; ++u) wv[u] = Ws[k][tx * CPT + u];
#pragma unroll
            for (int i = 0; i < 8; ++i)
#pragma unroll
                for (int u = 0; u < CPT; ++u) acc[i][u] = fmaf(a[i], wv[u], acc[i][u]);
        }
        __syncthreads();
    }
#pragma unroll
    for (int i = 0; i < 8; ++i) {
        int r = row0 + ty * 8 + i;
        if (r < n) {
#pragma unroll
            for (int u = 0; u < CPT; u += 4) {
                float4 v;
                v.x = acc[i][u + 0] + bias[tx * CPT + u + 0];
                v.y = acc[i][u + 1] + bias[tx * CPT + u + 1];
                v.z = acc[i][u + 2] + bias[tx * CPT + u + 2];
                v.w = acc[i][u + 3] + bias[tx * CPT + u + 3];
                if (GELU_EPI) {
                    v.x = gelu_f(v.x);
                    v.y = gelu_f(v.y);
                    v.z = gelu_f(v.z);
                    v.w = gelu_f(v.w);
                }
                *(float4*)&H[(size_t)r * DOUT + tx * CPT + u] = v;
            }
        }
    }
}

// ---------------- LN + GELU + residual (wave per row, D=128) ----------------

__global__ void k_post(const float* __restrict__ H, const float* __restrict__ Xin,
                       const float* __restrict__ g, const float* __restrict__ b,
                       float* __restrict__ Xout, int n) {
    const int wid = (blockIdx.x * blockDim.x + threadIdx.x) >> 6;
    const int lane = threadIdx.x & 63;
    const int nw = (gridDim.x * blockDim.x) >> 6;
    for (int i = wid; i < n; i += nw) {
        float h0 = H[(size_t)i * 128 + lane];
        float h1 = H[(size_t)i * 128 + 64 + lane];
        float mu = wave_sum(h0 + h1) * (1.0f / 128.0f);
        float d0 = h0 - mu, d1 = h1 - mu;
        float var = wave_sum(d0 * d0 + d1 * d1) * (1.0f / 128.0f);
        float rs = rsqrtf(var + 1e-5f);
        float y0 = gelu_f(d0 * rs * g[lane] + b[lane]) + Xin[(size_t)i * 128 + lane];
        float y1 = gelu_f(d1 * rs * g[64 + lane] + b[64 + lane]) + Xin[(size_t)i * 128 + 64 + lane];
        Xout[(size_t)i * 128 + lane] = y0;
        Xout[(size_t)i * 128 + 64 + lane] = y1;
    }
}

// ---------------- classifier: LN(x3) @ Wc + bcls (wave per row, 64 -> 40) ----------------

__global__ void k_cls(const float* __restrict__ X3, const float* __restrict__ g,
                      const float* __restrict__ b, const float* __restrict__ Wc,
                      const float* __restrict__ bcls, float* __restrict__ Out, int n) {
    const int wid = (blockIdx.x * blockDim.x + threadIdx.x) >> 6;
    const int lane = threadIdx.x & 63;
    const int nw = (gridDim.x * blockDim.x) >> 6;
    const int jj = lane < 40 ? lane : 0;
    for (int i = wid; i < n; i += nw) {
        float v = X3[(size_t)i * 64 + lane];
        float mu = wave_sum(v) * (1.0f / 64.0f);
        float d = v - mu;
        float var = wave_sum(d * d) * (1.0f / 64.0f);
        float y = d * rsqrtf(var + 1e-5f) * g[lane] + b[lane];
        float o = bcls[jj];
#pragma unroll 8
        for (int k = 0; k < 64; ++k) {
            float yk = __shfl(y, k);
            o = fmaf(yk, Wc[k * 40 + jj], o);
        }
        if (lane < 40) Out[(size_t)i * 40 + lane] = o;
    }
}

// ---------------------------------------------------------------------------

extern "C" void kernel_launch(void* const* d_in, const int* in_sizes, int n_in,
                              void* d_out, int out_size, void* d_ws, size_t ws_size,
                              hipStream_t stream) {
    const float* x   = (const float*)d_in[0];
    const int* ei    = (const int*)d_in[1];
    const float* Wl1 = (const float*)d_in[2];
    const float* bl1 = (const float*)d_in[3];
    const float* Wr1 = (const float*)d_in[4];
    const float* g1  = (const float*)d_in[5];
    const float* b1  = (const float*)d_in[6];
    const float* Wl2 = (const float*)d_in[7];
    const float* bl2 = (const float*)d_in[8];
    const float* Wr2 = (const float*)d_in[9];
    const float* g2  = (const float*)d_in[10];
    const float* b2  = (const float*)d_in[11];
    const float* Wl3 = (const float*)d_in[12];
    const float* bl3 = (const float*)d_in[13];
    const float* Wr3 = (const float*)d_in[14];
    const float* gc  = (const float*)d_in[15];
    const float* bc  = (const float*)d_in[16];
    const float* Wc  = (const float*)d_in[17];
    const float* bcls= (const float*)d_in[18];

    const int n = in_sizes[0] / 128;   // 50000
    const int e = in_sizes[1] / 2;     // 800000
    const int* src = ei;
    const int* dst = ei + e;

    char* w = (char*)d_ws;
    size_t o = 0;
    auto alloc = [&](size_t bytes) -> char* {
        char* p = w + o;
        o = (o + bytes + 511) & ~(size_t)511;
        return p;
    };
    int* cur   = (int*)alloc((size_t)n * 4);
    int* off   = (int*)alloc((size_t)(n + 1) * 4);
    int* csr   = (int*)alloc((size_t)e * 4);
    float* agg = (float*)alloc((size_t)n * 128 * 4);  // also used as H for layers 1-2
    float* xa  = (float*)alloc((size_t)n * 128 * 4);
    float* xb  = (float*)alloc((size_t)n * 128 * 4);
    float* x3  = (float*)alloc((size_t)n * 64 * 4);
    (void)ws_size;

    hipMemsetAsync(cur, 0, (size_t)n * 4, stream);
    k_count<<<1024, 256, 0, stream>>>(dst, cur, e);
    k_scan<<<1, 1024, 0, stream>>>(cur, off, n);
    k_fill<<<1024, 256, 0, stream>>>(src, dst, cur, csr, e);

    const int gemm_grid = (n + 127) / 128;

    // block 1
    k_agg<<<2048, 256, 0, stream>>>(x, off, csr, agg, n);
    k_gemm<128, false><<<gemm_grid, 256, 0, stream>>>(agg, x, Wl1, Wr1, bl1, agg, n);
    k_post<<<2048, 256, 0, stream>>>(agg, x, g1, b1, xa, n);
    // block 2
    k_agg<<<2048, 256, 0, stream>>>(xa, off, csr, agg, n);
    k_gemm<128, false><<<gemm_grid, 256, 0, stream>>>(agg, xa, Wl2, Wr2, bl2, agg, n);
    k_post<<<2048, 256, 0, stream>>>(agg, xa, g2, b2, xb, n);
    // conv_out + GELU
    k_agg<<<2048, 256, 0, stream>>>(xb, off, csr, agg, n);
    k_gemm<64, true><<<gemm_grid, 256, 0, stream>>>(agg, xb, Wl3, Wr3, bl3, x3, n);
    // classifier
    k_cls<<<2048, 256, 0, stream>>>(x3, gc, bc, Wc, bcls, (float*)d_out, n);
}

// Round 2
// 502.530 us; speedup vs baseline: 1.3411x; 1.3411x over previous
//
#include <hip/hip_runtime.h>
#include <math.h>

// ---------------------------------------------------------------------------
// CellTypeGNN: 2x [SAGE(mean) -> LN -> GELU -> +res] -> SAGE -> GELU -> LN -> Linear
// N=50000, E=800000, D=128, DOUT(conv3)=64, classes=40. fp32 throughout.
// R1: multi-block CSR scan (was 128us single-block); LN+GELU+residual fused
//     into GEMM epilogue (k_post eliminated); float2 gather in k_agg.
// ---------------------------------------------------------------------------

__device__ inline float gelu_f(float x) {
    return 0.5f * x * (1.0f + erff(x * 0.70710678118654752440f));
}

__device__ inline float wave_sum(float v) {
#pragma unroll
    for (int d = 32; d > 0; d >>= 1) v += __shfl_xor(v, d);
    return v;
}

// ---------------- CSR build ----------------

__global__ void k_count(const int* __restrict__ dst, int* __restrict__ cnt, int e) {
    int t = blockIdx.x * blockDim.x + threadIdx.x;
    int stride = gridDim.x * blockDim.x;
    for (int i = t; i < e; i += stride) {
        atomicAdd(&cnt[dst[i]], 1);
    }
}

// Pass 1: per-block (1024-elem chunk, 256 thr x 4) local exclusive scan of cnt
// into off; block total into part[bid].
__global__ __launch_bounds__(256) void k_scan1(const int* __restrict__ cnt,
                                               int* __restrict__ off,
                                               int* __restrict__ part, int n) {
    __shared__ int sm[256];
    const int tid = threadIdx.x;
    const int base = blockIdx.x * 1024 + tid * 4;
    int4 v = make_int4(0, 0, 0, 0);
    if (base + 3 < n) {
        v = *(const int4*)(cnt + base);
    } else {
        if (base + 0 < n) v.x = cnt[base + 0];
        if (base + 1 < n) v.y = cnt[base + 1];
        if (base + 2 < n) v.z = cnt[base + 2];
        if (base + 3 < n) v.w = cnt[base + 3];
    }
    int s = v.x + v.y + v.z + v.w;
    sm[tid] = s;
    __syncthreads();
#pragma unroll
    for (int d = 1; d < 256; d <<= 1) {
        int add = (tid >= d) ? sm[tid - d] : 0;
        __syncthreads();
        sm[tid] += add;
        __syncthreads();
    }
    int ex = (tid ? sm[tid - 1] : 0);
    if (base + 0 < n) off[base + 0] = ex;
    ex += v.x;
    if (base + 1 < n) off[base + 1] = ex;
    ex += v.y;
    if (base + 2 < n) off[base + 2] = ex;
    ex += v.z;
    if (base + 3 < n) off[base + 3] = ex;
    if (tid == 255) part[blockIdx.x] = sm[255];
}

// Pass 2: add block base (sum of preceding part[]) to off chunk; mirror to cur.
__global__ __launch_bounds__(256) void k_scan2(int* __restrict__ off, int* __restrict__ cur,
                                               const int* __restrict__ part, int nblk,
                                               int n, int e) {
    const int tid = threadIdx.x;
    const int bid = blockIdx.x;
    const int lane = tid & 63;
    int s = 0;
    for (int j = lane; j < bid; j += 64) s += part[j];
#pragma unroll
    for (int d = 32; d > 0; d >>= 1) s += __shfl_xor(s, d);
    const int base_val = s;
    const int i0 = bid * 1024 + tid * 4;
#pragma unroll
    for (int j = 0; j < 4; ++j) {
        int i = i0 + j;
        if (i < n) {
            int vv = off[i] + base_val;
            off[i] = vv;
            cur[i] = vv;
        }
    }
    if (bid == nblk - 1 && tid == 255) off[n] = e;
}

__global__ void k_fill(const int* __restrict__ src, const int* __restrict__ dst,
                       int* __restrict__ cur, int* __restrict__ csr, int e) {
    int t = blockIdx.x * blockDim.x + threadIdx.x;
    int stride = gridDim.x * blockDim.x;
    for (int i = t; i < e; i += stride) {
        int d = dst[i];
        int pos = atomicAdd(&cur[d], 1);
        csr[pos] = src[i];
    }
}

// ---------------- mean aggregation (wave per node, float2 lanes) ----------------

__global__ void k_agg(const float* __restrict__ X, const int* __restrict__ off,
                      const int* __restrict__ csr, float* __restrict__ agg, int n) {
    const int wid = (blockIdx.x * blockDim.x + threadIdx.x) >> 6;
    const int lane = threadIdx.x & 63;
    const int nw = (gridDim.x * blockDim.x) >> 6;
    for (int i = wid; i < n; i += nw) {
        int s0 = off[i], s1 = off[i + 1];
        float a0 = 0.f, a1 = 0.f;
        int t = s0;
        for (; t + 1 < s1; t += 2) {
            int i0 = csr[t], i1 = csr[t + 1];
            float2 v0 = *((const float2*)(X + (size_t)i0 * 128) + lane);
            float2 v1 = *((const float2*)(X + (size_t)i1 * 128) + lane);
            a0 += v0.x + v1.x;
            a1 += v0.y + v1.y;
        }
        if (t < s1) {
            float2 v0 = *((const float2*)(X + (size_t)csr[t] * 128) + lane);
            a0 += v0.x;
            a1 += v0.y;
        }
        int deg = s1 - s0;
        float inv = 1.0f / (float)(deg > 1 ? deg : 1);
        float2 r;
        r.x = a0 * inv;
        r.y = a1 * inv;
        *((float2*)(agg + (size_t)i * 128) + lane) = r;
    }
}

// ---------------- fused SAGE GEMM: Out = epi([Agg|Xin] @ [Wl;Wr] + bias) -------
// BM=128 rows, BN=DOUT cols (full width), BK=32. 256 threads, 8 rows x CPT cols.
// EPI: 0 = +bias; 1 = LN+GELU+residual(Xin); 2 = GELU.
// For EPI=1, a row's DOUT=128 cols live in an aligned 16-lane group (fixed ty),
// so LN reduces via __shfl_xor 1/2/4/8.

template <int DOUT, int EPI>
__global__ __launch_bounds__(256) void k_gemm(const float* __restrict__ Agg,
                                              const float* __restrict__ Xin,
                                              const float* __restrict__ Wl,
                                              const float* __restrict__ Wr,
                                              const float* __restrict__ bias,
                                              const float* __restrict__ g,
                                              const float* __restrict__ b,
                                              float* __restrict__ Out, int n) {
    __shared__ float As[128][33];
    __shared__ float Ws[32][DOUT];
    const int tid = threadIdx.x;
    const int tx = tid & 15;
    const int ty = tid >> 4;
    constexpr int CPT = DOUT / 16;  // 8 or 4
    const int row0 = blockIdx.x * 128;

    float acc[8][CPT];
#pragma unroll
    for (int i = 0; i < 8; ++i)
#pragma unroll
        for (int u = 0; u < CPT; ++u) acc[i][u] = 0.f;

    for (int k0 = 0; k0 < 256; k0 += 32) {
        const float* Asrc = (k0 < 128) ? Agg : Xin;
        const int kk = k0 & 127;
        {
            const int m = tid >> 1;
            const int cb = (tid & 1) * 16;
            int gr = row0 + m;
            if (gr > n - 1) gr = n - 1;
            const float* p = Asrc + (size_t)gr * 128 + kk + cb;
#pragma unroll
            for (int j = 0; j < 4; ++j) {
                float4 v = *(const float4*)(p + j * 4);
                As[m][cb + j * 4 + 0] = v.x;
                As[m][cb + j * 4 + 1] = v.y;
                As[m][cb + j * 4 + 2] = v.z;
                As[m][cb + j * 4 + 3] = v.w;
            }
        }
        {
            const float* Wsrc = ((k0 < 128) ? Wl : Wr) + (size_t)kk * DOUT;
            constexpr int FPT = (32 * DOUT) / 256;  // 16 or 8
#pragma unroll
            for (int j = 0; j < FPT / 4; ++j) {
                int flat = tid * FPT + j * 4;
                int r = flat / DOUT, c = flat % DOUT;
                float4 v = *(const float4*)(Wsrc + (size_t)r * DOUT + c);
                *(float4*)&Ws[r][c] = v;
            }
        }
        __syncthreads();
#pragma unroll
        for (int k = 0; k < 32; ++k) {
            float a[8], wv[CPT];
#pragma unroll
            for (int i = 0; i < 8; ++i) a[i] = As[ty * 8 + i][k];
#pragma unroll
            for (int u = 0; u < CPT; ++u) wv[u] = Ws[k][tx * CPT + u];
#pragma unroll
            for (int i = 0; i < 8; ++i)
#pragma unroll
                for (int u = 0; u < CPT; ++u) acc[i][u] = fmaf(a[i], wv[u], acc[i][u]);
        }
        __syncthreads();
    }

    // hoist per-column params
    float bv[CPT], gv[CPT], bbv[CPT];
#pragma unroll
    for (int u = 0; u < CPT; ++u) {
        int c = tx * CPT + u;
        bv[u] = bias[c];
        if (EPI == 1) {
            gv[u] = g[c];
            bbv[u] = b[c];
        }
    }

#pragma unroll
    for (int i = 0; i < 8; ++i) {
        int r = row0 + ty * 8 + i;  // uniform across the 16-lane group
        if (r >= n) continue;
        float v[CPT];
#pragma unroll
        for (int u = 0; u < CPT; ++u) v[u] = acc[i][u] + bv[u];
        if (EPI == 1) {
            float s = 0.f;
#pragma unroll
            for (int u = 0; u < CPT; ++u) s += v[u];
#pragma unroll
            for (int m = 1; m < 16; m <<= 1) s += __shfl_xor(s, m);
            float mu = s * (1.0f / (float)DOUT);
            float q = 0.f;
#pragma unroll
            for (int u = 0; u < CPT; ++u) {
                float d = v[u] - mu;
                q += d * d;
            }
#pragma unroll
            for (int m = 1; m < 16; m <<= 1) q += __shfl_xor(q, m);
            float rs = rsqrtf(q * (1.0f / (float)DOUT) + 1e-5f);
#pragma unroll
            for (int u = 0; u < CPT; ++u) {
                int c = tx * CPT + u;
                float y = (v[u] - mu) * rs * gv[u] + bbv[u];
                v[u] = gelu_f(y) + Xin[(size_t)r * DOUT + c];
            }
        } else if (EPI == 2) {
#pragma unroll
            for (int u = 0; u < CPT; ++u) v[u] = gelu_f(v[u]);
        }
#pragma unroll
        for (int u = 0; u < CPT; u += 4) {
            float4 o;
            o.x = v[u + 0];
            o.y = v[u + 1];
            o.z = v[u + 2];
            o.w = v[u + 3];
            *(float4*)&Out[(size_t)r * DOUT + tx * CPT + u] = o;
        }
    }
}

// ---------------- classifier: LN(x3) @ Wc + bcls (wave per row, 64 -> 40) ------

__global__ void k_cls(const float* __restrict__ X3, const float* __restrict__ g,
                      const float* __restrict__ b, const float* __restrict__ Wc,
                      const float* __restrict__ bcls, float* __restrict__ Out, int n) {
    const int wid = (blockIdx.x * blockDim.x + threadIdx.x) >> 6;
    const int lane = threadIdx.x & 63;
    const int nw = (gridDim.x * blockDim.x) >> 6;
    const int jj = lane < 40 ? lane : 0;
    for (int i = wid; i < n; i += nw) {
        float v = X3[(size_t)i * 64 + lane];
        float mu = wave_sum(v) * (1.0f / 64.0f);
        float d = v - mu;
        float var = wave_sum(d * d) * (1.0f / 64.0f);
        float y = d * rsqrtf(var + 1e-5f) * g[lane] + b[lane];
        float o = bcls[jj];
#pragma unroll 8
        for (int k = 0; k < 64; ++k) {
            float yk = __shfl(y, k);
            o = fmaf(yk, Wc[k * 40 + jj], o);
        }
        if (lane < 40) Out[(size_t)i * 40 + lane] = o;
    }
}

// ---------------------------------------------------------------------------

extern "C" void kernel_launch(void* const* d_in, const int* in_sizes, int n_in,
                              void* d_out, int out_size, void* d_ws, size_t ws_size,
                              hipStream_t stream) {
    const float* x   = (const float*)d_in[0];
    const int* ei    = (const int*)d_in[1];
    const float* Wl1 = (const float*)d_in[2];
    const float* bl1 = (const float*)d_in[3];
    const float* Wr1 = (const float*)d_in[4];
    const float* g1  = (const float*)d_in[5];
    const float* b1  = (const float*)d_in[6];
    const float* Wl2 = (const float*)d_in[7];
    const float* bl2 = (const float*)d_in[8];
    const float* Wr2 = (const float*)d_in[9];
    const float* g2  = (const float*)d_in[10];
    const float* b2  = (const float*)d_in[11];
    const float* Wl3 = (const float*)d_in[12];
    const float* bl3 = (const float*)d_in[13];
    const float* Wr3 = (const float*)d_in[14];
    const float* gc  = (const float*)d_in[15];
    const float* bc  = (const float*)d_in[16];
    const float* Wc  = (const float*)d_in[17];
    const float* bcls= (const float*)d_in[18];

    const int n = in_sizes[0] / 128;   // 50000
    const int e = in_sizes[1] / 2;     // 800000
    const int* src = ei;
    const int* dst = ei + e;

    char* w = (char*)d_ws;
    size_t o = 0;
    auto alloc = [&](size_t bytes) -> char* {
        char* p = w + o;
        o = (o + bytes + 511) & ~(size_t)511;
        return p;
    };
    int* cnt   = (int*)alloc((size_t)n * 4);
    int* cur   = (int*)alloc((size_t)n * 4);
    int* off   = (int*)alloc((size_t)(n + 1) * 4);
    int* part  = (int*)alloc(256 * 4);
    int* csr   = (int*)alloc((size_t)e * 4);
    float* agg = (float*)alloc((size_t)n * 128 * 4);
    float* xa  = (float*)alloc((size_t)n * 128 * 4);
    float* xb  = (float*)alloc((size_t)n * 128 * 4);
    float* x3  = (float*)alloc((size_t)n * 64 * 4);
    (void)ws_size;

    const int nblk = (n + 1023) / 1024;

    hipMemsetAsync(cnt, 0, (size_t)n * 4, stream);
    k_count<<<1024, 256, 0, stream>>>(dst, cnt, e);
    k_scan1<<<nblk, 256, 0, stream>>>(cnt, off, part, n);
    k_scan2<<<nblk, 256, 0, stream>>>(off, cur, part, nblk, n, e);
    k_fill<<<1024, 256, 0, stream>>>(src, dst, cur, csr, e);

    const int gemm_grid = (n + 127) / 128;

    // block 1
    k_agg<<<2048, 256, 0, stream>>>(x, off, csr, agg, n);
    k_gemm<128, 1><<<gemm_grid, 256, 0, stream>>>(agg, x, Wl1, Wr1, bl1, g1, b1, xa, n);
    // block 2
    k_agg<<<2048, 256, 0, stream>>>(xa, off, csr, agg, n);
    k_gemm<128, 1><<<gemm_grid, 256, 0, stream>>>(agg, xa, Wl2, Wr2, bl2, g2, b2, xb, n);
    // conv_out + GELU
    k_agg<<<2048, 256, 0, stream>>>(xb, off, csr, agg, n);
    k_gemm<64, 2><<<gemm_grid, 256, 0, stream>>>(agg, xb, Wl3, Wr3, bl3, nullptr, nullptr, x3, n);
    // classifier
    k_cls<<<2048, 256, 0, stream>>>(x3, gc, bc, Wc, bcls, (float*)d_out, n);
}

// Round 4
// 435.352 us; speedup vs baseline: 1.5481x; 1.1543x over previous
//
#include <hip/hip_runtime.h>
#include <math.h>

// ---------------------------------------------------------------------------
// CellTypeGNN: 2x [SAGE(mean) -> LN -> GELU -> +res] -> SAGE -> GELU -> LN -> Linear
// N=50000, E=800000, D=128, DOUT(conv3)=64, classes=40.
// R3: fix R2's LN bug — LN must reduce across all 128 cols of a row, which are
//     split across the 4 waves in the MFMA tiling. Cross-wave LN via 2KB LDS
//     partials (sum, sumsq). Everything else unchanged from R2.
// ---------------------------------------------------------------------------

typedef __attribute__((ext_vector_type(8))) short bf16x8;
typedef __attribute__((ext_vector_type(4))) float f32x4;

__device__ inline float gelu_f(float x) {
    return 0.5f * x * (1.0f + erff(x * 0.70710678118654752440f));
}

__device__ inline float wave_sum(float v) {
#pragma unroll
    for (int d = 32; d > 0; d >>= 1) v += __shfl_xor(v, d);
    return v;
}

__device__ inline ushort f2b(float f) {  // fp32 -> bf16 RNE
    uint u = __float_as_uint(f);
    u += 0x7fffu + ((u >> 16) & 1u);
    return (ushort)(u >> 16);
}

// ---------------- CSR build ----------------

__global__ void k_count(const int* __restrict__ dst, int* __restrict__ cnt, int e) {
    int t = blockIdx.x * blockDim.x + threadIdx.x;
    int stride = gridDim.x * blockDim.x;
    for (int i = t; i < e; i += stride) atomicAdd(&cnt[dst[i]], 1);
}

__global__ __launch_bounds__(256) void k_scan1(const int* __restrict__ cnt,
                                               int* __restrict__ off,
                                               int* __restrict__ part, int n) {
    __shared__ int sm[256];
    const int tid = threadIdx.x;
    const int base = blockIdx.x * 1024 + tid * 4;
    int4 v = make_int4(0, 0, 0, 0);
    if (base + 3 < n) {
        v = *(const int4*)(cnt + base);
    } else {
        if (base + 0 < n) v.x = cnt[base + 0];
        if (base + 1 < n) v.y = cnt[base + 1];
        if (base + 2 < n) v.z = cnt[base + 2];
        if (base + 3 < n) v.w = cnt[base + 3];
    }
    int s = v.x + v.y + v.z + v.w;
    sm[tid] = s;
    __syncthreads();
#pragma unroll
    for (int d = 1; d < 256; d <<= 1) {
        int add = (tid >= d) ? sm[tid - d] : 0;
        __syncthreads();
        sm[tid] += add;
        __syncthreads();
    }
    int ex = (tid ? sm[tid - 1] : 0);
    if (base + 0 < n) off[base + 0] = ex;
    ex += v.x;
    if (base + 1 < n) off[base + 1] = ex;
    ex += v.y;
    if (base + 2 < n) off[base + 2] = ex;
    ex += v.z;
    if (base + 3 < n) off[base + 3] = ex;
    if (tid == 255) part[blockIdx.x] = sm[255];
}

__global__ __launch_bounds__(256) void k_scan2(int* __restrict__ off, int* __restrict__ cur,
                                               const int* __restrict__ part, int nblk,
                                               int n, int e) {
    const int tid = threadIdx.x;
    const int bid = blockIdx.x;
    const int lane = tid & 63;
    int s = 0;
    for (int j = lane; j < bid; j += 64) s += part[j];
#pragma unroll
    for (int d = 32; d > 0; d >>= 1) s += __shfl_xor(s, d);
    const int base_val = s;
    const int i0 = bid * 1024 + tid * 4;
#pragma unroll
    for (int j = 0; j < 4; ++j) {
        int i = i0 + j;
        if (i < n) {
            int vv = off[i] + base_val;
            off[i] = vv;
            cur[i] = vv;
        }
    }
    if (bid == nblk - 1 && tid == 255) off[n] = e;
}

__global__ void k_fill(const int* __restrict__ src, const int* __restrict__ dst,
                       int* __restrict__ cur, int* __restrict__ csr, int e) {
    int t = blockIdx.x * blockDim.x + threadIdx.x;
    int stride = gridDim.x * blockDim.x;
    for (int i = t; i < e; i += stride) {
        int d = dst[i];
        int pos = atomicAdd(&cur[d], 1);
        csr[pos] = src[i];
    }
}

// ---------------- casts ----------------

__global__ void k_cast(const float* __restrict__ in, ushort* __restrict__ out, int nvec4) {
    int t = blockIdx.x * blockDim.x + threadIdx.x;
    int stride = gridDim.x * blockDim.x;
    for (int i = t; i < nvec4; i += stride) {
        float4 v = ((const float4*)in)[i];
        ushort4 o;
        o.x = f2b(v.x);
        o.y = f2b(v.y);
        o.z = f2b(v.z);
        o.w = f2b(v.w);
        ((ushort4*)out)[i] = o;
    }
}

// Wt[c][k] = (k<KH ? Wl[k][c] : Wr[k-KH][c]); Wt is [C][2*KH] bf16.
__global__ void k_wprep(const float* __restrict__ Wl, const float* __restrict__ Wr,
                        int KH, int C, ushort* __restrict__ Wt) {
    int t = blockIdx.x * blockDim.x + threadIdx.x;
    int total = C * 2 * KH;
    if (t >= total) return;
    int c = t / (2 * KH), k = t % (2 * KH);
    float v = (k < KH) ? Wl[(size_t)k * C + c] : Wr[(size_t)(k - KH) * C + c];
    Wt[t] = f2b(v);
}

// ---------------- mean aggregation (bf16 in/out, fp32 accumulate) ----------------

__global__ void k_agg(const ushort* __restrict__ X, const int* __restrict__ off,
                      const int* __restrict__ csr, ushort* __restrict__ agg, int n) {
    const int wid = (blockIdx.x * blockDim.x + threadIdx.x) >> 6;
    const int lane = threadIdx.x & 63;
    const int nw = (gridDim.x * blockDim.x) >> 6;
    for (int i = wid; i < n; i += nw) {
        int s0 = off[i], s1 = off[i + 1];
        float a0 = 0.f, a1 = 0.f;
        int t = s0;
        for (; t + 1 < s1; t += 2) {
            uint u0 = *((const uint*)(X + (size_t)csr[t] * 128) + lane);
            uint u1 = *((const uint*)(X + (size_t)csr[t + 1] * 128) + lane);
            a0 += __uint_as_float(u0 << 16) + __uint_as_float(u1 << 16);
            a1 += __uint_as_float(u0 & 0xffff0000u) + __uint_as_float(u1 & 0xffff0000u);
        }
        if (t < s1) {
            uint u0 = *((const uint*)(X + (size_t)csr[t] * 128) + lane);
            a0 += __uint_as_float(u0 << 16);
            a1 += __uint_as_float(u0 & 0xffff0000u);
        }
        int deg = s1 - s0;
        float inv = 1.0f / (float)(deg > 1 ? deg : 1);
        uint pk = (uint)f2b(a0 * inv) | ((uint)f2b(a1 * inv) << 16);
        *((uint*)(agg + (size_t)i * 128) + lane) = pk;
    }
}

// ---------------- MFMA SAGE GEMM ----------------
// C = [Agg | Xb] @ Wt^T + bias, then EPI (1: LN+GELU+res, 2: GELU).
// 256 thr = 4 waves; block tile 64 rows x DOUT cols; wave tile 64 x (CT*16).
// 16x16x32 bf16 MFMA. A/B frags use identical k-placement (k = ks*32+g4*8+j),
// so the contraction is k-permutation-invariant. C/D: col=lane&15,
// row=(lane>>4)*4+reg [m89-verified].
// EPI==1 LN: a row's 128 cols are split across the 4 waves -> cross-wave
// reduction via LDS partials (sum, sumsq).

template <int DOUT, int EPI>
__global__ __launch_bounds__(256) void k_gemm(
    const ushort* __restrict__ Agg,   // [n][128] bf16
    const ushort* __restrict__ Xb,    // [n][128] bf16
    const float* __restrict__ Xres,   // [n][128] f32 (EPI==1)
    const ushort* __restrict__ Wt,    // [DOUT][256] bf16
    const float* __restrict__ bias, const float* __restrict__ g,
    const float* __restrict__ b,
    float* __restrict__ OutF,         // [n][DOUT]
    ushort* __restrict__ OutB,        // [n][DOUT] bf16 (EPI==1)
    int n) {
    constexpr int CT = DOUT / 64;  // col-tiles per wave: 2 (DOUT=128) or 1 (64)
    const int tid = threadIdx.x;
    const int wave = tid >> 6;
    const int lane = tid & 63;
    const int l16 = lane & 15;
    const int g4 = lane >> 4;
    const int row0 = blockIdx.x * 64;

    // preload B fragments (registers, reused across all rows)
    bf16x8 bfr[CT][8];
#pragma unroll
    for (int ct = 0; ct < CT; ++ct) {
        int col = (wave * CT + ct) * 16 + l16;
        const ushort* wp = Wt + (size_t)col * 256 + g4 * 8;
#pragma unroll
        for (int ks = 0; ks < 8; ++ks) bfr[ct][ks] = *(const bf16x8*)(wp + ks * 32);
    }

    f32x4 acc[4][CT];
#pragma unroll
    for (int rt = 0; rt < 4; ++rt)
#pragma unroll
        for (int ct = 0; ct < CT; ++ct) {
            acc[rt][ct][0] = 0.f;
            acc[rt][ct][1] = 0.f;
            acc[rt][ct][2] = 0.f;
            acc[rt][ct][3] = 0.f;
        }

    int arow[4];
#pragma unroll
    for (int rt = 0; rt < 4; ++rt) {
        int r = row0 + rt * 16 + l16;
        arow[rt] = (r < n) ? r : (n - 1);
    }

#pragma unroll
    for (int ks = 0; ks < 8; ++ks) {
        const ushort* Ak = (ks < 4) ? (Agg + ks * 32) : (Xb + (ks - 4) * 32);
#pragma unroll
        for (int rt = 0; rt < 4; ++rt) {
            bf16x8 a = *(const bf16x8*)(Ak + (size_t)arow[rt] * 128 + g4 * 8);
#pragma unroll
            for (int ct = 0; ct < CT; ++ct)
                acc[rt][ct] = __builtin_amdgcn_mfma_f32_16x16x32_bf16(a, bfr[ct][ks],
                                                                      acc[rt][ct], 0, 0, 0);
        }
    }

    // epilogue
    float biasv[CT], gv[CT], bbv[CT];
    int colv[CT];
#pragma unroll
    for (int ct = 0; ct < CT; ++ct) {
        int col = (wave * CT + ct) * 16 + l16;
        colv[ct] = col;
        biasv[ct] = bias[col];
        if (EPI == 1) {
            gv[ct] = g[col];
            bbv[ct] = b[col];
        }
    }

    if (EPI == 1) {
        __shared__ float sP[64][4];
        __shared__ float qP[64][4];
        // v[rt][reg][ct] = acc + bias; per-(row,wave) partial sum/sumsq
        float v[4][4][CT];
        float sv[4][4], qv[4][4];
#pragma unroll
        for (int rt = 0; rt < 4; ++rt)
#pragma unroll
            for (int reg = 0; reg < 4; ++reg) {
                float s = 0.f, q = 0.f;
#pragma unroll
                for (int ct = 0; ct < CT; ++ct) {
                    float t = acc[rt][ct][reg] + biasv[ct];
                    v[rt][reg][ct] = t;
                    s += t;
                    q += t * t;
                }
                sv[rt][reg] = s;
                qv[rt][reg] = q;
            }
#pragma unroll
        for (int m = 1; m < 16; m <<= 1)
#pragma unroll
            for (int rt = 0; rt < 4; ++rt)
#pragma unroll
                for (int reg = 0; reg < 4; ++reg) {
                    sv[rt][reg] += __shfl_xor(sv[rt][reg], m);
                    qv[rt][reg] += __shfl_xor(qv[rt][reg], m);
                }
        if (l16 == 0) {
#pragma unroll
            for (int rt = 0; rt < 4; ++rt)
#pragma unroll
                for (int reg = 0; reg < 4; ++reg) {
                    int rib = rt * 16 + g4 * 4 + reg;
                    sP[rib][wave] = sv[rt][reg];
                    qP[rib][wave] = qv[rt][reg];
                }
        }
        __syncthreads();
#pragma unroll
        for (int rt = 0; rt < 4; ++rt) {
#pragma unroll
            for (int reg = 0; reg < 4; ++reg) {
                int rib = rt * 16 + g4 * 4 + reg;
                float s = sP[rib][0] + sP[rib][1] + sP[rib][2] + sP[rib][3];
                float q = qP[rib][0] + qP[rib][1] + qP[rib][2] + qP[rib][3];
                float mu = s * (1.0f / 128.0f);
                float var = q * (1.0f / 128.0f) - mu * mu;
                float rs = rsqrtf(fmaxf(var, 0.f) + 1e-5f);
                int r = row0 + rib;
                if (r >= n) continue;
#pragma unroll
                for (int ct = 0; ct < CT; ++ct) {
                    float y = (v[rt][reg][ct] - mu) * rs * gv[ct] + bbv[ct];
                    y = gelu_f(y) + Xres[(size_t)r * 128 + colv[ct]];
                    OutF[(size_t)r * 128 + colv[ct]] = y;
                    OutB[(size_t)r * 128 + colv[ct]] = f2b(y);
                }
            }
        }
    } else {
#pragma unroll
        for (int rt = 0; rt < 4; ++rt)
#pragma unroll
            for (int reg = 0; reg < 4; ++reg) {
                int r = row0 + rt * 16 + g4 * 4 + reg;
                if (r >= n) continue;
#pragma unroll
                for (int ct = 0; ct < CT; ++ct)
                    OutF[(size_t)r * DOUT + colv[ct]] = gelu_f(acc[rt][ct][reg] + biasv[ct]);
            }
    }
}

// ---------------- classifier: LN(x3) @ Wc + bcls (wave per row, 64 -> 40) ------

__global__ void k_cls(const float* __restrict__ X3, const float* __restrict__ g,
                      const float* __restrict__ b, const float* __restrict__ Wc,
                      const float* __restrict__ bcls, float* __restrict__ Out, int n) {
    const int wid = (blockIdx.x * blockDim.x + threadIdx.x) >> 6;
    const int lane = threadIdx.x & 63;
    const int nw = (gridDim.x * blockDim.x) >> 6;
    const int jj = lane < 40 ? lane : 0;
    for (int i = wid; i < n; i += nw) {
        float v = X3[(size_t)i * 64 + lane];
        float mu = wave_sum(v) * (1.0f / 64.0f);
        float d = v - mu;
        float var = wave_sum(d * d) * (1.0f / 64.0f);
        float y = d * rsqrtf(var + 1e-5f) * g[lane] + b[lane];
        float o = bcls[jj];
#pragma unroll 8
        for (int k = 0; k < 64; ++k) {
            float yk = __shfl(y, k);
            o = fmaf(yk, Wc[k * 40 + jj], o);
        }
        if (lane < 40) Out[(size_t)i * 40 + lane] = o;
    }
}

// ---------------------------------------------------------------------------

extern "C" void kernel_launch(void* const* d_in, const int* in_sizes, int n_in,
                              void* d_out, int out_size, void* d_ws, size_t ws_size,
                              hipStream_t stream) {
    const float* x   = (const float*)d_in[0];
    const int* ei    = (const int*)d_in[1];
    const float* Wl1 = (const float*)d_in[2];
    const float* bl1 = (const float*)d_in[3];
    const float* Wr1 = (const float*)d_in[4];
    const float* g1  = (const float*)d_in[5];
    const float* b1  = (const float*)d_in[6];
    const float* Wl2 = (const float*)d_in[7];
    const float* bl2 = (const float*)d_in[8];
    const float* Wr2 = (const float*)d_in[9];
    const float* g2  = (const float*)d_in[10];
    const float* b2  = (const float*)d_in[11];
    const float* Wl3 = (const float*)d_in[12];
    const float* bl3 = (const float*)d_in[13];
    const float* Wr3 = (const float*)d_in[14];
    const float* gc  = (const float*)d_in[15];
    const float* bc  = (const float*)d_in[16];
    const float* Wc  = (const float*)d_in[17];
    const float* bcls= (const float*)d_in[18];

    const int n = in_sizes[0] / 128;  // 50000
    const int e = in_sizes[1] / 2;    // 800000
    const int* src = ei;
    const int* dst = ei + e;

    char* w = (char*)d_ws;
    size_t o = 0;
    auto alloc = [&](size_t bytes) -> char* {
        char* p = w + o;
        o = (o + bytes + 511) & ~(size_t)511;
        return p;
    };
    int* cnt     = (int*)alloc((size_t)n * 4);
    int* cur     = (int*)alloc((size_t)n * 4);
    int* off     = (int*)alloc((size_t)(n + 1) * 4);
    int* part    = (int*)alloc(256 * 4);
    int* csr     = (int*)alloc((size_t)e * 4);
    ushort* xB   = (ushort*)alloc((size_t)n * 128 * 2);
    ushort* aggB = (ushort*)alloc((size_t)n * 128 * 2);
    float* xaF   = (float*)alloc((size_t)n * 128 * 4);
    ushort* xaB  = (ushort*)alloc((size_t)n * 128 * 2);
    float* xbF   = (float*)alloc((size_t)n * 128 * 4);
    ushort* xbB  = (ushort*)alloc((size_t)n * 128 * 2);
    float* x3    = (float*)alloc((size_t)n * 64 * 4);
    ushort* W1t  = (ushort*)alloc((size_t)128 * 256 * 2);
    ushort* W2t  = (ushort*)alloc((size_t)128 * 256 * 2);
    ushort* W3t  = (ushort*)alloc((size_t)64 * 256 * 2);
    (void)ws_size;

    const int nblk = (n + 1023) / 1024;

    hipMemsetAsync(cnt, 0, (size_t)n * 4, stream);
    k_count<<<1024, 256, 0, stream>>>(dst, cnt, e);
    k_scan1<<<nblk, 256, 0, stream>>>(cnt, off, part, n);
    k_scan2<<<nblk, 256, 0, stream>>>(off, cur, part, nblk, n, e);
    k_fill<<<1024, 256, 0, stream>>>(src, dst, cur, csr, e);

    k_cast<<<2048, 256, 0, stream>>>(x, xB, n * 128 / 4);
    k_wprep<<<(128 * 256 + 255) / 256, 256, 0, stream>>>(Wl1, Wr1, 128, 128, W1t);
    k_wprep<<<(128 * 256 + 255) / 256, 256, 0, stream>>>(Wl2, Wr2, 128, 128, W2t);
    k_wprep<<<(64 * 256 + 255) / 256, 256, 0, stream>>>(Wl3, Wr3, 128, 64, W3t);

    const int gg = (n + 63) / 64;

    // block 1
    k_agg<<<2048, 256, 0, stream>>>(xB, off, csr, aggB, n);
    k_gemm<128, 1><<<gg, 256, 0, stream>>>(aggB, xB, x, W1t, bl1, g1, b1, xaF, xaB, n);
    // block 2
    k_agg<<<2048, 256, 0, stream>>>(xaB, off, csr, aggB, n);
    k_gemm<128, 1><<<gg, 256, 0, stream>>>(aggB, xaB, xaF, W2t, bl2, g2, b2, xbF, xbB, n);
    // conv_out + GELU
    k_agg<<<2048, 256, 0, stream>>>(xbB, off, csr, aggB, n);
    k_gemm<64, 2><<<gg, 256, 0, stream>>>(aggB, xbB, nullptr, W3t, bl3, nullptr, nullptr, x3,
                                          nullptr, n);
    // classifier
    k_cls<<<2048, 256, 0, stream>>>(x3, gc, bc, Wc, bcls, (float*)d_out, n);
}

// Round 5
// 341.097 us; speedup vs baseline: 1.9759x; 1.2763x over previous
//
#include <hip/hip_runtime.h>
#include <math.h>

// ---------------------------------------------------------------------------
// CellTypeGNN: 2x [SAGE(mean) -> LN -> GELU -> +res] -> SAGE -> GELU -> LN -> Linear
// N=50000, E=800000, D=128, DOUT(conv3)=64, classes=40.
// R4: bf16-only residual stream (EPI1 writes/reads bf16 only, -38MB/layer);
//     k_gemm BM=32 (2x blocks, shorter per-wave chains); k_agg caches the
//     CSR slice in registers via __shfl (1 coalesced csr load/node) with
//     4-deep row gathers.
// ---------------------------------------------------------------------------

typedef __attribute__((ext_vector_type(8))) short bf16x8;
typedef __attribute__((ext_vector_type(4))) float f32x4;

__device__ inline float gelu_f(float x) {
    return 0.5f * x * (1.0f + erff(x * 0.70710678118654752440f));
}

__device__ inline float wave_sum(float v) {
#pragma unroll
    for (int d = 32; d > 0; d >>= 1) v += __shfl_xor(v, d);
    return v;
}

__device__ inline ushort f2b(float f) {  // fp32 -> bf16 RNE
    uint u = __float_as_uint(f);
    u += 0x7fffu + ((u >> 16) & 1u);
    return (ushort)(u >> 16);
}

__device__ inline float b2f(ushort h) { return __uint_as_float((uint)h << 16); }

// ---------------- CSR build ----------------

__global__ void k_count(const int* __restrict__ dst, int* __restrict__ cnt, int e) {
    int t = blockIdx.x * blockDim.x + threadIdx.x;
    int stride = gridDim.x * blockDim.x;
    for (int i = t; i < e; i += stride) atomicAdd(&cnt[dst[i]], 1);
}

__global__ __launch_bounds__(256) void k_scan1(const int* __restrict__ cnt,
                                               int* __restrict__ off,
                                               int* __restrict__ part, int n) {
    __shared__ int sm[256];
    const int tid = threadIdx.x;
    const int base = blockIdx.x * 1024 + tid * 4;
    int4 v = make_int4(0, 0, 0, 0);
    if (base + 3 < n) {
        v = *(const int4*)(cnt + base);
    } else {
        if (base + 0 < n) v.x = cnt[base + 0];
        if (base + 1 < n) v.y = cnt[base + 1];
        if (base + 2 < n) v.z = cnt[base + 2];
        if (base + 3 < n) v.w = cnt[base + 3];
    }
    int s = v.x + v.y + v.z + v.w;
    sm[tid] = s;
    __syncthreads();
#pragma unroll
    for (int d = 1; d < 256; d <<= 1) {
        int add = (tid >= d) ? sm[tid - d] : 0;
        __syncthreads();
        sm[tid] += add;
        __syncthreads();
    }
    int ex = (tid ? sm[tid - 1] : 0);
    if (base + 0 < n) off[base + 0] = ex;
    ex += v.x;
    if (base + 1 < n) off[base + 1] = ex;
    ex += v.y;
    if (base + 2 < n) off[base + 2] = ex;
    ex += v.z;
    if (base + 3 < n) off[base + 3] = ex;
    if (tid == 255) part[blockIdx.x] = sm[255];
}

__global__ __launch_bounds__(256) void k_scan2(int* __restrict__ off, int* __restrict__ cur,
                                               const int* __restrict__ part, int nblk,
                                               int n, int e) {
    const int tid = threadIdx.x;
    const int bid = blockIdx.x;
    const int lane = tid & 63;
    int s = 0;
    for (int j = lane; j < bid; j += 64) s += part[j];
#pragma unroll
    for (int d = 32; d > 0; d >>= 1) s += __shfl_xor(s, d);
    const int base_val = s;
    const int i0 = bid * 1024 + tid * 4;
#pragma unroll
    for (int j = 0; j < 4; ++j) {
        int i = i0 + j;
        if (i < n) {
            int vv = off[i] + base_val;
            off[i] = vv;
            cur[i] = vv;
        }
    }
    if (bid == nblk - 1 && tid == 255) off[n] = e;
}

__global__ void k_fill(const int* __restrict__ src, const int* __restrict__ dst,
                       int* __restrict__ cur, int* __restrict__ csr, int e) {
    int t = blockIdx.x * blockDim.x + threadIdx.x;
    int stride = gridDim.x * blockDim.x;
    for (int i = t; i < e; i += stride) {
        int d = dst[i];
        int pos = atomicAdd(&cur[d], 1);
        csr[pos] = src[i];
    }
}

// ---------------- casts ----------------

__global__ void k_cast(const float* __restrict__ in, ushort* __restrict__ out, int nvec4) {
    int t = blockIdx.x * blockDim.x + threadIdx.x;
    int stride = gridDim.x * blockDim.x;
    for (int i = t; i < nvec4; i += stride) {
        float4 v = ((const float4*)in)[i];
        ushort4 o;
        o.x = f2b(v.x);
        o.y = f2b(v.y);
        o.z = f2b(v.z);
        o.w = f2b(v.w);
        ((ushort4*)out)[i] = o;
    }
}

// Wt[c][k] = (k<KH ? Wl[k][c] : Wr[k-KH][c]); Wt is [C][2*KH] bf16.
__global__ void k_wprep(const float* __restrict__ Wl, const float* __restrict__ Wr,
                        int KH, int C, ushort* __restrict__ Wt) {
    int t = blockIdx.x * blockDim.x + threadIdx.x;
    int total = C * 2 * KH;
    if (t >= total) return;
    int c = t / (2 * KH), k = t % (2 * KH);
    float v = (k < KH) ? Wl[(size_t)k * C + c] : Wr[(size_t)(k - KH) * C + c];
    Wt[t] = f2b(v);
}

// ---------------- mean aggregation (bf16 in/out, fp32 accumulate) ----------------
// Wave per node. One coalesced csr load covers the first 64 neighbors; indices
// are then distributed by __shfl (no per-iteration csr latency). Row gathers
// run 4 deep. deg>64 tail falls back to direct csr loads (never hit for
// Poisson(16), kept for correctness).

__global__ void k_agg(const ushort* __restrict__ X, const int* __restrict__ off,
                      const int* __restrict__ csr, ushort* __restrict__ agg, int n) {
    const int wid = (blockIdx.x * blockDim.x + threadIdx.x) >> 6;
    const int lane = threadIdx.x & 63;
    const int nw = (gridDim.x * blockDim.x) >> 6;
    for (int i = wid; i < n; i += nw) {
        int s0 = off[i], s1 = off[i + 1];
        int deg = s1 - s0;
        int c = 0;
        if (s0 + lane < s1) c = csr[s0 + lane];
        float a0 = 0.f, a1 = 0.f;
        const int dcap = deg < 64 ? deg : 64;
        int t = 0;
        for (; t + 3 < dcap; t += 4) {
            int i0 = __shfl(c, t), i1 = __shfl(c, t + 1);
            int i2 = __shfl(c, t + 2), i3 = __shfl(c, t + 3);
            uint u0 = *((const uint*)(X + (size_t)i0 * 128) + lane);
            uint u1 = *((const uint*)(X + (size_t)i1 * 128) + lane);
            uint u2 = *((const uint*)(X + (size_t)i2 * 128) + lane);
            uint u3 = *((const uint*)(X + (size_t)i3 * 128) + lane);
            a0 += __uint_as_float(u0 << 16) + __uint_as_float(u1 << 16) +
                  __uint_as_float(u2 << 16) + __uint_as_float(u3 << 16);
            a1 += __uint_as_float(u0 & 0xffff0000u) + __uint_as_float(u1 & 0xffff0000u) +
                  __uint_as_float(u2 & 0xffff0000u) + __uint_as_float(u3 & 0xffff0000u);
        }
        for (; t < dcap; ++t) {
            uint u0 = *((const uint*)(X + (size_t)__shfl(c, t) * 128) + lane);
            a0 += __uint_as_float(u0 << 16);
            a1 += __uint_as_float(u0 & 0xffff0000u);
        }
        for (int tt = s0 + 64; tt < s1; ++tt) {  // rare deg>64 tail
            uint u0 = *((const uint*)(X + (size_t)csr[tt] * 128) + lane);
            a0 += __uint_as_float(u0 << 16);
            a1 += __uint_as_float(u0 & 0xffff0000u);
        }
        float inv = 1.0f / (float)(deg > 1 ? deg : 1);
        uint pk = (uint)f2b(a0 * inv) | ((uint)f2b(a1 * inv) << 16);
        *((uint*)(agg + (size_t)i * 128) + lane) = pk;
    }
}

// ---------------- MFMA SAGE GEMM ----------------
// C = [Agg | Xb] @ Wt^T + bias, then EPI (1: LN+GELU+res -> bf16; 2: GELU -> f32).
// 256 thr = 4 waves; block tile 32 rows x DOUT cols; wave tile 32 x (CT*16).
// 16x16x32 bf16 MFMA, A/B same k-placement (k-permutation-invariant).
// C/D: col=lane&15, row=(lane>>4)*4+reg [m89-verified].
// EPI==1 LN: row's 128 cols split across 4 waves -> cross-wave LDS partials.

template <int DOUT, int EPI>
__global__ __launch_bounds__(256) void k_gemm(
    const ushort* __restrict__ Agg,   // [n][128] bf16
    const ushort* __restrict__ Xb,    // [n][128] bf16
    const ushort* __restrict__ Xres,  // [n][128] bf16 residual (EPI==1)
    const ushort* __restrict__ Wt,    // [DOUT][256] bf16
    const float* __restrict__ bias, const float* __restrict__ g,
    const float* __restrict__ b,
    ushort* __restrict__ OutB,        // [n][128] bf16 (EPI==1)
    float* __restrict__ OutF,         // [n][DOUT] f32 (EPI==2)
    int n) {
    constexpr int CT = DOUT / 64;  // 2 (DOUT=128) or 1 (64)
    const int tid = threadIdx.x;
    const int wave = tid >> 6;
    const int lane = tid & 63;
    const int l16 = lane & 15;
    const int g4 = lane >> 4;
    const int row0 = blockIdx.x * 32;

    // B fragments in registers (reused across rows)
    bf16x8 bfr[CT][8];
#pragma unroll
    for (int ct = 0; ct < CT; ++ct) {
        int col = (wave * CT + ct) * 16 + l16;
        const ushort* wp = Wt + (size_t)col * 256 + g4 * 8;
#pragma unroll
        for (int ks = 0; ks < 8; ++ks) bfr[ct][ks] = *(const bf16x8*)(wp + ks * 32);
    }

    f32x4 acc[2][CT];
#pragma unroll
    for (int rt = 0; rt < 2; ++rt)
#pragma unroll
        for (int ct = 0; ct < CT; ++ct) {
            acc[rt][ct][0] = 0.f;
            acc[rt][ct][1] = 0.f;
            acc[rt][ct][2] = 0.f;
            acc[rt][ct][3] = 0.f;
        }

    int arow[2];
#pragma unroll
    for (int rt = 0; rt < 2; ++rt) {
        int r = row0 + rt * 16 + l16;
        arow[rt] = (r < n) ? r : (n - 1);
    }

#pragma unroll
    for (int ks = 0; ks < 8; ++ks) {
        const ushort* Ak = (ks < 4) ? (Agg + ks * 32) : (Xb + (ks - 4) * 32);
#pragma unroll
        for (int rt = 0; rt < 2; ++rt) {
            bf16x8 a = *(const bf16x8*)(Ak + (size_t)arow[rt] * 128 + g4 * 8);
#pragma unroll
            for (int ct = 0; ct < CT; ++ct)
                acc[rt][ct] = __builtin_amdgcn_mfma_f32_16x16x32_bf16(a, bfr[ct][ks],
                                                                      acc[rt][ct], 0, 0, 0);
        }
    }

    float biasv[CT], gv[CT], bbv[CT];
    int colv[CT];
#pragma unroll
    for (int ct = 0; ct < CT; ++ct) {
        int col = (wave * CT + ct) * 16 + l16;
        colv[ct] = col;
        biasv[ct] = bias[col];
        if (EPI == 1) {
            gv[ct] = g[col];
            bbv[ct] = b[col];
        }
    }

    if (EPI == 1) {
        __shared__ float sP[32][4];
        __shared__ float qP[32][4];
        float v[2][4][CT];
        float sv[2][4], qv[2][4];
#pragma unroll
        for (int rt = 0; rt < 2; ++rt)
#pragma unroll
            for (int reg = 0; reg < 4; ++reg) {
                float s = 0.f, q = 0.f;
#pragma unroll
                for (int ct = 0; ct < CT; ++ct) {
                    float t = acc[rt][ct][reg] + biasv[ct];
                    v[rt][reg][ct] = t;
                    s += t;
                    q += t * t;
                }
                sv[rt][reg] = s;
                qv[rt][reg] = q;
            }
#pragma unroll
        for (int m = 1; m < 16; m <<= 1)
#pragma unroll
            for (int rt = 0; rt < 2; ++rt)
#pragma unroll
                for (int reg = 0; reg < 4; ++reg) {
                    sv[rt][reg] += __shfl_xor(sv[rt][reg], m);
                    qv[rt][reg] += __shfl_xor(qv[rt][reg], m);
                }
        if (l16 == 0) {
#pragma unroll
            for (int rt = 0; rt < 2; ++rt)
#pragma unroll
                for (int reg = 0; reg < 4; ++reg) {
                    int rib = rt * 16 + g4 * 4 + reg;
                    sP[rib][wave] = sv[rt][reg];
                    qP[rib][wave] = qv[rt][reg];
                }
        }
        __syncthreads();
#pragma unroll
        for (int rt = 0; rt < 2; ++rt) {
#pragma unroll
            for (int reg = 0; reg < 4; ++reg) {
                int rib = rt * 16 + g4 * 4 + reg;
                float s = sP[rib][0] + sP[rib][1] + sP[rib][2] + sP[rib][3];
                float q = qP[rib][0] + qP[rib][1] + qP[rib][2] + qP[rib][3];
                float mu = s * (1.0f / 128.0f);
                float var = q * (1.0f / 128.0f) - mu * mu;
                float rs = rsqrtf(fmaxf(var, 0.f) + 1e-5f);
                int r = row0 + rib;
                if (r >= n) continue;
#pragma unroll
                for (int ct = 0; ct < CT; ++ct) {
                    float y = (v[rt][reg][ct] - mu) * rs * gv[ct] + bbv[ct];
                    y = gelu_f(y) + b2f(Xres[(size_t)r * 128 + colv[ct]]);
                    OutB[(size_t)r * 128 + colv[ct]] = f2b(y);
                }
            }
        }
    } else {
#pragma unroll
        for (int rt = 0; rt < 2; ++rt)
#pragma unroll
            for (int reg = 0; reg < 4; ++reg) {
                int r = row0 + rt * 16 + g4 * 4 + reg;
                if (r >= n) continue;
#pragma unroll
                for (int ct = 0; ct < CT; ++ct)
                    OutF[(size_t)r * DOUT + colv[ct]] = gelu_f(acc[rt][ct][reg] + biasv[ct]);
            }
    }
}

// ---------------- classifier: LN(x3) @ Wc + bcls (wave per row, 64 -> 40) ------

__global__ void k_cls(const float* __restrict__ X3, const float* __restrict__ g,
                      const float* __restrict__ b, const float* __restrict__ Wc,
                      const float* __restrict__ bcls, float* __restrict__ Out, int n) {
    const int wid = (blockIdx.x * blockDim.x + threadIdx.x) >> 6;
    const int lane = threadIdx.x & 63;
    const int nw = (gridDim.x * blockDim.x) >> 6;
    const int jj = lane < 40 ? lane : 0;
    for (int i = wid; i < n; i += nw) {
        float v = X3[(size_t)i * 64 + lane];
        float mu = wave_sum(v) * (1.0f / 64.0f);
        float d = v - mu;
        float var = wave_sum(d * d) * (1.0f / 64.0f);
        float y = d * rsqrtf(var + 1e-5f) * g[lane] + b[lane];
        float o = bcls[jj];
#pragma unroll 8
        for (int k = 0; k < 64; ++k) {
            float yk = __shfl(y, k);
            o = fmaf(yk, Wc[k * 40 + jj], o);
        }
        if (lane < 40) Out[(size_t)i * 40 + lane] = o;
    }
}

// ---------------------------------------------------------------------------

extern "C" void kernel_launch(void* const* d_in, const int* in_sizes, int n_in,
                              void* d_out, int out_size, void* d_ws, size_t ws_size,
                              hipStream_t stream) {
    const float* x   = (const float*)d_in[0];
    const int* ei    = (const int*)d_in[1];
    const float* Wl1 = (const float*)d_in[2];
    const float* bl1 = (const float*)d_in[3];
    const float* Wr1 = (const float*)d_in[4];
    const float* g1  = (const float*)d_in[5];
    const float* b1  = (const float*)d_in[6];
    const float* Wl2 = (const float*)d_in[7];
    const float* bl2 = (const float*)d_in[8];
    const float* Wr2 = (const float*)d_in[9];
    const float* g2  = (const float*)d_in[10];
    const float* b2  = (const float*)d_in[11];
    const float* Wl3 = (const float*)d_in[12];
    const float* bl3 = (const float*)d_in[13];
    const float* Wr3 = (const float*)d_in[14];
    const float* gc  = (const float*)d_in[15];
    const float* bc  = (const float*)d_in[16];
    const float* Wc  = (const float*)d_in[17];
    const float* bcls= (const float*)d_in[18];

    const int n = in_sizes[0] / 128;  // 50000
    const int e = in_sizes[1] / 2;    // 800000
    const int* src = ei;
    const int* dst = ei + e;

    char* w = (char*)d_ws;
    size_t o = 0;
    auto alloc = [&](size_t bytes) -> char* {
        char* p = w + o;
        o = (o + bytes + 511) & ~(size_t)511;
        return p;
    };
    int* cnt     = (int*)alloc((size_t)n * 4);
    int* cur     = (int*)alloc((size_t)n * 4);
    int* off     = (int*)alloc((size_t)(n + 1) * 4);
    int* part    = (int*)alloc(256 * 4);
    int* csr     = (int*)alloc((size_t)e * 4);
    ushort* xB   = (ushort*)alloc((size_t)n * 128 * 2);
    ushort* aggB = (ushort*)alloc((size_t)n * 128 * 2);
    ushort* xaB  = (ushort*)alloc((size_t)n * 128 * 2);
    ushort* xbB  = (ushort*)alloc((size_t)n * 128 * 2);
    float* x3    = (float*)alloc((size_t)n * 64 * 4);
    ushort* W1t  = (ushort*)alloc((size_t)128 * 256 * 2);
    ushort* W2t  = (ushort*)alloc((size_t)128 * 256 * 2);
    ushort* W3t  = (ushort*)alloc((size_t)64 * 256 * 2);
    (void)ws_size;

    const int nblk = (n + 1023) / 1024;

    hipMemsetAsync(cnt, 0, (size_t)n * 4, stream);
    k_count<<<1024, 256, 0, stream>>>(dst, cnt, e);
    k_scan1<<<nblk, 256, 0, stream>>>(cnt, off, part, n);
    k_scan2<<<nblk, 256, 0, stream>>>(off, cur, part, nblk, n, e);
    k_fill<<<1024, 256, 0, stream>>>(src, dst, cur, csr, e);

    k_cast<<<2048, 256, 0, stream>>>(x, xB, n * 128 / 4);
    k_wprep<<<(128 * 256 + 255) / 256, 256, 0, stream>>>(Wl1, Wr1, 128, 128, W1t);
    k_wprep<<<(128 * 256 + 255) / 256, 256, 0, stream>>>(Wl2, Wr2, 128, 128, W2t);
    k_wprep<<<(64 * 256 + 255) / 256, 256, 0, stream>>>(Wl3, Wr3, 128, 64, W3t);

    const int gg = (n + 31) / 32;

    // block 1
    k_agg<<<2048, 256, 0, stream>>>(xB, off, csr, aggB, n);
    k_gemm<128, 1><<<gg, 256, 0, stream>>>(aggB, xB, xB, W1t, bl1, g1, b1, xaB, nullptr, n);
    // block 2
    k_agg<<<2048, 256, 0, stream>>>(xaB, off, csr, aggB, n);
    k_gemm<128, 1><<<gg, 256, 0, stream>>>(aggB, xaB, xaB, W2t, bl2, g2, b2, xbB, nullptr, n);
    // conv_out + GELU
    k_agg<<<2048, 256, 0, stream>>>(xbB, off, csr, aggB, n);
    k_gemm<64, 2><<<gg, 256, 0, stream>>>(aggB, xbB, nullptr, W3t, bl3, nullptr, nullptr,
                                          nullptr, x3, n);
    // classifier
    k_cls<<<2048, 256, 0, stream>>>(x3, gc, bc, Wc, bcls, (float*)d_out, n);
}